// Round 1
// baseline (2075.695 us; speedup 1.0000x reference)
//
#include <hip/hip_runtime.h>
#include <hip/hip_bf16.h>
#include <stdint.h>

#define TTOK 2048
#define DDIM 2048
#define IDIM 5632
#define NEXP 8

#define BM 128
#define BNG 64
#define BK 32
#define LD 48  // padded LDS stride (bf16 elems) = 96B: 16B-aligned rows, reduced bank conflicts

typedef __attribute__((ext_vector_type(8))) short bf16x8;
typedef __attribute__((ext_vector_type(4))) float f32x4;
typedef __attribute__((ext_vector_type(8))) unsigned short u16x8;
typedef __attribute__((ext_vector_type(4))) unsigned short u16x4;

__device__ __forceinline__ unsigned short f2bf(float f) {
  union { float f; uint32_t u; } v; v.f = f;
  uint32_t u = v.u + 0x7fffu + ((v.u >> 16) & 1u);
  return (unsigned short)(u >> 16);
}

// ---------------- router: logits, top-2, softmax, expert lists, x->bf16 ----------------
__global__ __launch_bounds__(256) void router_kernel(
    const float* __restrict__ x, const float* __restrict__ gw,
    unsigned short* __restrict__ xbf,
    int* __restrict__ cnt, int* __restrict__ slots, float* __restrict__ wts)
{
  const int lane = threadIdx.x & 63;
  const int t = (blockIdx.x * blockDim.x + threadIdx.x) >> 6;  // one wave per token
  const float* xr = x + (size_t)t * DDIM;
  float acc[NEXP];
#pragma unroll
  for (int e = 0; e < NEXP; ++e) acc[e] = 0.f;
#pragma unroll
  for (int it = 0; it < DDIM / 256; ++it) {
    const int d = (it * 64 + lane) * 4;
    const float4 xv = *(const float4*)(xr + d);
    u16x4 xb; xb[0]=f2bf(xv.x); xb[1]=f2bf(xv.y); xb[2]=f2bf(xv.z); xb[3]=f2bf(xv.w);
    *(u16x4*)(xbf + (size_t)t * DDIM + d) = xb;
#pragma unroll
    for (int e = 0; e < NEXP; ++e) {
      const float4 gv = *(const float4*)(gw + (size_t)e * DDIM + d);
      acc[e] += xv.x*gv.x + xv.y*gv.y + xv.z*gv.z + xv.w*gv.w;
    }
  }
#pragma unroll
  for (int e = 0; e < NEXP; ++e) {
    float v = acc[e];
#pragma unroll
    for (int off = 32; off > 0; off >>= 1) v += __shfl_xor(v, off);
    acc[e] = v;
  }
  if (lane == 0) {
    int i0 = 0; float v0 = acc[0];
#pragma unroll
    for (int e = 1; e < NEXP; ++e) if (acc[e] > v0) { v0 = acc[e]; i0 = e; }
    int i1 = -1; float v1 = -3.4e38f;
#pragma unroll
    for (int e = 0; e < NEXP; ++e) { if (e == i0) continue; if (acc[e] > v1) { v1 = acc[e]; i1 = e; } }
    const float e1 = __expf(v1 - v0);
    const float w0 = 1.f / (1.f + e1);
    const float w1 = e1 / (1.f + e1);
    const int p0 = atomicAdd(&cnt[i0], 1);
    slots[i0 * TTOK + p0] = t * 2;     wts[i0 * TTOK + p0] = w0;
    const int p1 = atomicAdd(&cnt[i1], 1);
    slots[i1 * TTOK + p1] = t * 2 + 1; wts[i1 * TTOK + p1] = w1;
  }
}

// ---------------- gate+up grouped GEMM, fused silu*mul -> h (bf16) ----------------
__global__ __launch_bounds__(256) void gateup_kernel(
    const unsigned short* __restrict__ xbf,
    const float* __restrict__ wg, const float* __restrict__ wu,
    const int* __restrict__ cnt, const int* __restrict__ slots,
    unsigned short* __restrict__ h)
{
  const int e = blockIdx.x >> 4;
  const int mt = blockIdx.x & 15;
  const int count = cnt[e];
  const int m0 = mt * BM;
  if (m0 >= count) return;
  const int n0 = blockIdx.y * BNG;

  __shared__ unsigned short A[BM][LD];
  __shared__ unsigned short Bg[BNG][LD];
  __shared__ unsigned short Bu[BNG][LD];
  __shared__ int rtok[BM];
  __shared__ int rslot[BM];

  const int tid = threadIdx.x;
  if (tid < BM) {
    const int idx = m0 + tid;
    const int safe = slots[e * TTOK + m0];
    const int s = (idx < count) ? slots[e * TTOK + idx] : safe;
    rslot[tid] = (idx < count) ? s : -1;
    rtok[tid] = s >> 1;
  }
  __syncthreads();

  const int lane = tid & 63;
  const int wid = tid >> 6;
  const int wr = wid >> 1;
  const int wc = wid & 1;
  const int fr = lane & 15;
  const int fk = (lane >> 4) * 8;

  f32x4 accg[4][2] = {};
  f32x4 accu[4][2] = {};
  const size_t wbase = (size_t)e * IDIM * DDIM;

#pragma unroll 1
  for (int k0 = 0; k0 < DDIM; k0 += BK) {
    __syncthreads();
#pragma unroll
    for (int j = 0; j < 2; ++j) {  // A: 128x32 bf16, gathered token rows
      const int c = tid + j * 256;
      const int row = c >> 2, cb = c & 3;
      *(u16x8*)&A[row][cb * 8] =
        *(const u16x8*)(xbf + (size_t)rtok[row] * DDIM + k0 + cb * 8);
    }
#pragma unroll
    for (int j = 0; j < 2; ++j) {  // B: 64x32 f32 x2 matrices -> bf16
      const int c = tid + j * 256;
      const int row = c >> 3, c4 = c & 7;
      const size_t off = wbase + (size_t)(n0 + row) * DDIM + k0 + c4 * 4;
      const float4 g4 = *(const float4*)(wg + off);
      const float4 u4 = *(const float4*)(wu + off);
      u16x4 gb; gb[0]=f2bf(g4.x); gb[1]=f2bf(g4.y); gb[2]=f2bf(g4.z); gb[3]=f2bf(g4.w);
      u16x4 ub; ub[0]=f2bf(u4.x); ub[1]=f2bf(u4.y); ub[2]=f2bf(u4.z); ub[3]=f2bf(u4.w);
      *(u16x4*)&Bg[row][c4 * 4] = gb;
      *(u16x4*)&Bu[row][c4 * 4] = ub;
    }
    __syncthreads();

    bf16x8 a[4], bg[2], bu[2];
#pragma unroll
    for (int mf = 0; mf < 4; ++mf)
      a[mf] = *(const bf16x8*)&A[wr * 64 + mf * 16 + fr][fk];
#pragma unroll
    for (int nf = 0; nf < 2; ++nf) {
      bg[nf] = *(const bf16x8*)&Bg[wc * 32 + nf * 16 + fr][fk];
      bu[nf] = *(const bf16x8*)&Bu[wc * 32 + nf * 16 + fr][fk];
    }
#pragma unroll
    for (int mf = 0; mf < 4; ++mf)
#pragma unroll
      for (int nf = 0; nf < 2; ++nf) {
        accg[mf][nf] = __builtin_amdgcn_mfma_f32_16x16x32_bf16(a[mf], bg[nf], accg[mf][nf], 0, 0, 0);
        accu[mf][nf] = __builtin_amdgcn_mfma_f32_16x16x32_bf16(a[mf], bu[nf], accu[mf][nf], 0, 0, 0);
      }
  }

#pragma unroll
  for (int mf = 0; mf < 4; ++mf)
#pragma unroll
    for (int nf = 0; nf < 2; ++nf)
#pragma unroll
      for (int j = 0; j < 4; ++j) {
        const int r = wr * 64 + mf * 16 + (lane >> 4) * 4 + j;
        const int s = rslot[r];
        if (s >= 0) {
          const float g = accg[mf][nf][j];
          const float u = accu[mf][nf][j];
          const float hv = g / (1.f + __expf(-g)) * u;
          h[(size_t)s * IDIM + n0 + wc * 32 + nf * 16 + fr] = f2bf(hv);
        }
      }
}

// ---------------- down grouped GEMM, scaled scatter-add into out ----------------
__global__ __launch_bounds__(256) void down_kernel(
    const unsigned short* __restrict__ h,
    const float* __restrict__ wd,
    const int* __restrict__ cnt, const int* __restrict__ slots,
    const float* __restrict__ wts,
    float* __restrict__ out)
{
  const int e = blockIdx.x >> 4;
  const int mt = blockIdx.x & 15;
  const int count = cnt[e];
  const int m0 = mt * BM;
  if (m0 >= count) return;
  const int n0 = blockIdx.y * 128;

  __shared__ unsigned short A[BM][LD];
  __shared__ unsigned short B[128][LD];
  __shared__ int rslot[BM];
  __shared__ float rw[BM];

  const int tid = threadIdx.x;
  if (tid < BM) {
    const int idx = m0 + tid;
    const int safe = slots[e * TTOK + m0];
    const int s = (idx < count) ? slots[e * TTOK + idx] : safe;
    rslot[tid] = (idx < count) ? s : (safe | 0x40000000);  // keep addr valid, mark invalid
    rw[tid] = (idx < count) ? wts[e * TTOK + idx] : 0.f;
  }
  __syncthreads();

  const int lane = tid & 63;
  const int wid = tid >> 6;
  const int wr = wid >> 1;
  const int wc = wid & 1;
  const int fr = lane & 15;
  const int fk = (lane >> 4) * 8;

  f32x4 acc[4][4] = {};
  const size_t wbase = (size_t)e * DDIM * IDIM;

#pragma unroll 1
  for (int k0 = 0; k0 < IDIM; k0 += BK) {
    __syncthreads();
#pragma unroll
    for (int j = 0; j < 2; ++j) {  // A: gathered h rows
      const int c = tid + j * 256;
      const int row = c >> 2, cb = c & 3;
      const int s = rslot[row] & 0x3fffffff;
      *(u16x8*)&A[row][cb * 8] =
        *(const u16x8*)(h + (size_t)s * IDIM + k0 + cb * 8);
    }
#pragma unroll
    for (int j = 0; j < 4; ++j) {  // B: 128x32 f32 -> bf16
      const int c = tid + j * 256;
      const int row = c >> 3, c4 = c & 7;
      const float4 b4 = *(const float4*)(wd + wbase + (size_t)(n0 + row) * IDIM + k0 + c4 * 4);
      u16x4 bb; bb[0]=f2bf(b4.x); bb[1]=f2bf(b4.y); bb[2]=f2bf(b4.z); bb[3]=f2bf(b4.w);
      *(u16x4*)&B[row][c4 * 4] = bb;
    }
    __syncthreads();

    bf16x8 a[4], b[4];
#pragma unroll
    for (int mf = 0; mf < 4; ++mf)
      a[mf] = *(const bf16x8*)&A[wr * 64 + mf * 16 + fr][fk];
#pragma unroll
    for (int nf = 0; nf < 4; ++nf)
      b[nf] = *(const bf16x8*)&B[wc * 64 + nf * 16 + fr][fk];
#pragma unroll
    for (int mf = 0; mf < 4; ++mf)
#pragma unroll
      for (int nf = 0; nf < 4; ++nf)
        acc[mf][nf] = __builtin_amdgcn_mfma_f32_16x16x32_bf16(a[mf], b[nf], acc[mf][nf], 0, 0, 0);
  }

#pragma unroll
  for (int mf = 0; mf < 4; ++mf)
#pragma unroll
    for (int j = 0; j < 4; ++j) {
      const int r = wr * 64 + mf * 16 + (lane >> 4) * 4 + j;
      const int s = rslot[r];
      if (!(s & 0x40000000)) {
        const int t = s >> 1;
        const float w = rw[r];
#pragma unroll
        for (int nf = 0; nf < 4; ++nf)
          atomicAdd(out + (size_t)t * DDIM + n0 + wc * 64 + nf * 16 + fr,
                    acc[mf][nf][j] * w);
      }
    }
}

extern "C" void kernel_launch(void* const* d_in, const int* in_sizes, int n_in,
                              void* d_out, int out_size, void* d_ws, size_t ws_size,
                              hipStream_t stream) {
  const float* x  = (const float*)d_in[0];
  const float* gw = (const float*)d_in[1];
  const float* wg = (const float*)d_in[2];
  const float* wu = (const float*)d_in[3];
  const float* wd = (const float*)d_in[4];
  float* out = (float*)d_out;

  char* ws = (char*)d_ws;
  unsigned short* xbf = (unsigned short*)ws;                       // 8,388,608 B
  unsigned short* h   = (unsigned short*)(ws + 8388608);           // 46,137,344 B
  int*   slots = (int*)(ws + 8388608 + 46137344);                  // 65,536 B
  float* wts   = (float*)(ws + 8388608 + 46137344 + 65536);        // 65,536 B
  int*   cnt   = (int*)(ws + 8388608 + 46137344 + 131072);         // 32 B

  hipMemsetAsync(cnt, 0, NEXP * sizeof(int), stream);
  hipMemsetAsync(d_out, 0, (size_t)TTOK * DDIM * sizeof(float), stream);

  router_kernel<<<TTOK / 4, 256, 0, stream>>>(x, gw, xbf, cnt, slots, wts);
  gateup_kernel<<<dim3(NEXP * 16, IDIM / BNG), 256, 0, stream>>>(xbf, wg, wu, cnt, slots, h);
  down_kernel<<<dim3(NEXP * 16, DDIM / 128), 256, 0, stream>>>(h, wd, cnt, slots, wts, out);
}

// Round 2
// 1108.584 us; speedup vs baseline: 1.8724x; 1.8724x over previous
//
#include <hip/hip_runtime.h>
#include <hip/hip_bf16.h>
#include <stdint.h>

#define TTOK 2048
#define DDIM 2048
#define IDIM 5632
#define NEXP 8

typedef __attribute__((ext_vector_type(8))) short bf16x8;
typedef __attribute__((ext_vector_type(4))) float f32x4;
typedef __attribute__((ext_vector_type(8))) unsigned short u16x8;
typedef __attribute__((ext_vector_type(4))) unsigned short u16x4;

__device__ __forceinline__ unsigned short f2bf(float f) {
  union { float f; uint32_t u; } v; v.f = f;
  uint32_t u = v.u + 0x7fffu + ((v.u >> 16) & 1u);
  return (unsigned short)(u >> 16);
}

__device__ __forceinline__ u16x8 cvt8(float4 a, float4 b) {
  u16x8 r;
  r[0]=f2bf(a.x); r[1]=f2bf(a.y); r[2]=f2bf(a.z); r[3]=f2bf(a.w);
  r[4]=f2bf(b.x); r[5]=f2bf(b.y); r[6]=f2bf(b.z); r[7]=f2bf(b.w);
  return r;
}

typedef __attribute__((address_space(3))) void lds_t;
typedef const __attribute__((address_space(1))) void gbl_t;
__device__ __forceinline__ void gload16(const void* g, void* l) {
  __builtin_amdgcn_global_load_lds((gbl_t*)g, (lds_t*)l, 16, 0, 0);
}

// ---------------- router: logits, top-2, softmax, expert lists, x->bf16 ----------------
__global__ __launch_bounds__(256) void router_kernel(
    const float* __restrict__ x, const float* __restrict__ gw,
    unsigned short* __restrict__ xbf,
    int* __restrict__ cnt, int* __restrict__ slots, float* __restrict__ wts)
{
  const int lane = threadIdx.x & 63;
  const int t = (blockIdx.x * blockDim.x + threadIdx.x) >> 6;  // one wave per token
  const float* xr = x + (size_t)t * DDIM;
  float acc[NEXP];
#pragma unroll
  for (int e = 0; e < NEXP; ++e) acc[e] = 0.f;
#pragma unroll
  for (int it = 0; it < DDIM / 256; ++it) {
    const int d = (it * 64 + lane) * 4;
    const float4 xv = *(const float4*)(xr + d);
    u16x4 xb; xb[0]=f2bf(xv.x); xb[1]=f2bf(xv.y); xb[2]=f2bf(xv.z); xb[3]=f2bf(xv.w);
    *(u16x4*)(xbf + (size_t)t * DDIM + d) = xb;
#pragma unroll
    for (int e = 0; e < NEXP; ++e) {
      const float4 gv = *(const float4*)(gw + (size_t)e * DDIM + d);
      acc[e] += xv.x*gv.x + xv.y*gv.y + xv.z*gv.z + xv.w*gv.w;
    }
  }
#pragma unroll
  for (int e = 0; e < NEXP; ++e) {
    float v = acc[e];
#pragma unroll
    for (int off = 32; off > 0; off >>= 1) v += __shfl_xor(v, off);
    acc[e] = v;
  }
  if (lane == 0) {
    int i0 = 0; float v0 = acc[0];
#pragma unroll
    for (int e = 1; e < NEXP; ++e) if (acc[e] > v0) { v0 = acc[e]; i0 = e; }
    int i1 = -1; float v1 = -3.4e38f;
#pragma unroll
    for (int e = 0; e < NEXP; ++e) { if (e == i0) continue; if (acc[e] > v1) { v1 = acc[e]; i1 = e; } }
    const float e1 = __expf(v1 - v0);
    const float w0 = 1.f / (1.f + e1);
    const float w1 = e1 / (1.f + e1);
    const int p0 = atomicAdd(&cnt[i0], 1);
    slots[i0 * TTOK + p0] = t * 2;     wts[i0 * TTOK + p0] = w0;
    const int p1 = atomicAdd(&cnt[i1], 1);
    slots[i1 * TTOK + p1] = t * 2 + 1; wts[i1 * TTOK + p1] = w1;
  }
}

// ---------------- gate+up grouped GEMM: 128M x 64N x(2 mats), BK=64, gload_lds A ----------------
__global__ __launch_bounds__(256) void gateup_kernel(
    const unsigned short* __restrict__ xbf,
    const float* __restrict__ wg, const float* __restrict__ wu,
    const int* __restrict__ cnt, const int* __restrict__ slots,
    unsigned short* __restrict__ h)
{
  // XCD-aware swizzle (nwg=11264, q=1408), mt fastest within a chunk -> panel reuse in one XCD's L2
  const int L = (blockIdx.x & 7) * 1408 + (blockIdx.x >> 3);
  const int mt = L & 15;
  const int n0 = ((L >> 4) % 88) * 64;
  const int e  = L / (16 * 88);
  const int count = cnt[e];
  const int m0 = mt * 128;
  if (m0 >= count) return;

  __shared__ unsigned short A[128][64];
  __shared__ unsigned short Bg[64][64];
  __shared__ unsigned short Bu[64][64];
  __shared__ int rslot[128];
  __shared__ int rtok[128];

  const int tid = threadIdx.x;
  const int lane = tid & 63;
  const int wid = tid >> 6;

  if (tid < 128) {
    const int idx = m0 + tid;
    const int safe = slots[e * TTOK + m0];
    const int s = (idx < count) ? slots[e * TTOK + idx] : safe;
    rslot[tid] = (idx < count) ? s : -1;
    rtok[tid] = s >> 1;
  }
  __syncthreads();

  // A staging: per-lane gathered global src (fixed rows across K), wave-uniform LDS dest
  const unsigned short* aptr[4];
#pragma unroll
  for (int j = 0; j < 4; ++j) {
    const int arow = wid * 32 + j * 8 + (lane >> 3);
    aptr[j] = xbf + (size_t)rtok[arow] * DDIM + (lane & 7) * 8;
  }
  unsigned short* abase = &A[wid * 32][0];

  // B staging: 16 fp32 per thread per matrix
  const int brow = tid >> 2;
  const int bseg = (tid & 3) * 16;
  const size_t wboff = (size_t)e * IDIM * DDIM + (size_t)(n0 + brow) * DDIM + bseg;
  const float* gsrc = wg + wboff;
  const float* usrc = wu + wboff;

  const int wr = wid >> 1, wc = wid & 1;
  const int fr = lane & 15, fk = (lane >> 4) * 8;

  f32x4 accg[4][2] = {};
  f32x4 accu[4][2] = {};

#pragma unroll 1
  for (int k0 = 0; k0 < DDIM; k0 += 64) {
    __syncthreads();
#pragma unroll
    for (int j = 0; j < 4; ++j) gload16(aptr[j] + k0, abase + j * 512);
    float4 g4[4], u4[4];
#pragma unroll
    for (int q = 0; q < 4; ++q) {
      g4[q] = *(const float4*)(gsrc + k0 + q * 4);
      u4[q] = *(const float4*)(usrc + k0 + q * 4);
    }
    *(u16x8*)&Bg[brow][bseg]     = cvt8(g4[0], g4[1]);
    *(u16x8*)&Bg[brow][bseg + 8] = cvt8(g4[2], g4[3]);
    *(u16x8*)&Bu[brow][bseg]     = cvt8(u4[0], u4[1]);
    *(u16x8*)&Bu[brow][bseg + 8] = cvt8(u4[2], u4[3]);
    __syncthreads();

#pragma unroll
    for (int kk = 0; kk < 2; ++kk) {
      bf16x8 a[4], bg[2], bu[2];
#pragma unroll
      for (int mf = 0; mf < 4; ++mf)
        a[mf] = *(const bf16x8*)&A[wr * 64 + mf * 16 + fr][kk * 32 + fk];
#pragma unroll
      for (int nf = 0; nf < 2; ++nf) {
        bg[nf] = *(const bf16x8*)&Bg[wc * 32 + nf * 16 + fr][kk * 32 + fk];
        bu[nf] = *(const bf16x8*)&Bu[wc * 32 + nf * 16 + fr][kk * 32 + fk];
      }
#pragma unroll
      for (int mf = 0; mf < 4; ++mf)
#pragma unroll
        for (int nf = 0; nf < 2; ++nf) {
          accg[mf][nf] = __builtin_amdgcn_mfma_f32_16x16x32_bf16(a[mf], bg[nf], accg[mf][nf], 0, 0, 0);
          accu[mf][nf] = __builtin_amdgcn_mfma_f32_16x16x32_bf16(a[mf], bu[nf], accu[mf][nf], 0, 0, 0);
        }
    }
  }

#pragma unroll
  for (int mf = 0; mf < 4; ++mf)
#pragma unroll
    for (int nf = 0; nf < 2; ++nf)
#pragma unroll
      for (int j = 0; j < 4; ++j) {
        const int r = wr * 64 + mf * 16 + (lane >> 4) * 4 + j;
        const int s = rslot[r];
        if (s >= 0) {
          const float g = accg[mf][nf][j];
          const float u = accu[mf][nf][j];
          const float hv = g / (1.f + __expf(-g)) * u;
          h[(size_t)s * IDIM + n0 + wc * 32 + nf * 16 + fr] = f2bf(hv);
        }
      }
}

// ---------------- down grouped GEMM: 128M x 128N, BK=64, scaled scatter-add ----------------
__global__ __launch_bounds__(256) void down_kernel(
    const unsigned short* __restrict__ h,
    const float* __restrict__ wd,
    const int* __restrict__ cnt, const int* __restrict__ slots,
    const float* __restrict__ wts,
    float* __restrict__ out)
{
  // XCD-aware swizzle (nwg=2048, q=256), mt fastest
  const int L = (blockIdx.x & 7) * 256 + (blockIdx.x >> 3);
  const int mt = L & 15;
  const int n0 = ((L >> 4) & 15) * 128;
  const int e  = L >> 8;
  const int count = cnt[e];
  const int m0 = mt * 128;
  if (m0 >= count) return;

  __shared__ unsigned short A[128][64];
  __shared__ unsigned short B[128][64];
  __shared__ int rslot[128];
  __shared__ float rw[128];

  const int tid = threadIdx.x;
  const int lane = tid & 63;
  const int wid = tid >> 6;

  if (tid < 128) {
    const int idx = m0 + tid;
    const int safe = slots[e * TTOK + m0];
    const int s = (idx < count) ? slots[e * TTOK + idx] : safe;
    rslot[tid] = (idx < count) ? s : (safe | 0x40000000);
    rw[tid] = (idx < count) ? wts[e * TTOK + idx] : 0.f;
  }
  __syncthreads();

  const unsigned short* aptr[4];
#pragma unroll
  for (int j = 0; j < 4; ++j) {
    const int arow = wid * 32 + j * 8 + (lane >> 3);
    aptr[j] = h + (size_t)(rslot[arow] & 0x3fffffff) * IDIM + (lane & 7) * 8;
  }
  unsigned short* abase = &A[wid * 32][0];

  // B staging: 32 fp32 per thread
  const int brow = tid >> 1;
  const int bseg = (tid & 1) * 32;
  const float* bsrc = wd + (size_t)e * DDIM * IDIM + (size_t)(n0 + brow) * IDIM + bseg;

  const int wr = wid >> 1, wc = wid & 1;
  const int fr = lane & 15, fk = (lane >> 4) * 8;

  f32x4 acc[4][4] = {};

#pragma unroll 1
  for (int k0 = 0; k0 < IDIM; k0 += 64) {
    __syncthreads();
#pragma unroll
    for (int j = 0; j < 4; ++j) gload16(aptr[j] + k0, abase + j * 512);
    float4 b4[8];
#pragma unroll
    for (int q = 0; q < 8; ++q) b4[q] = *(const float4*)(bsrc + k0 + q * 4);
#pragma unroll
    for (int q = 0; q < 4; ++q)
      *(u16x8*)&B[brow][bseg + q * 8] = cvt8(b4[q * 2], b4[q * 2 + 1]);
    __syncthreads();

#pragma unroll
    for (int kk = 0; kk < 2; ++kk) {
      bf16x8 a[4], b[4];
#pragma unroll
      for (int mf = 0; mf < 4; ++mf)
        a[mf] = *(const bf16x8*)&A[wr * 64 + mf * 16 + fr][kk * 32 + fk];
#pragma unroll
      for (int nf = 0; nf < 4; ++nf)
        b[nf] = *(const bf16x8*)&B[wc * 64 + nf * 16 + fr][kk * 32 + fk];
#pragma unroll
      for (int mf = 0; mf < 4; ++mf)
#pragma unroll
        for (int nf = 0; nf < 4; ++nf)
          acc[mf][nf] = __builtin_amdgcn_mfma_f32_16x16x32_bf16(a[mf], b[nf], acc[mf][nf], 0, 0, 0);
    }
  }

#pragma unroll
  for (int mf = 0; mf < 4; ++mf)
#pragma unroll
    for (int j = 0; j < 4; ++j) {
      const int r = wr * 64 + mf * 16 + (lane >> 4) * 4 + j;
      const int s = rslot[r];
      if (!(s & 0x40000000)) {
        const int t = s >> 1;
        const float w = rw[r];
#pragma unroll
        for (int nf = 0; nf < 4; ++nf)
          atomicAdd(out + (size_t)t * DDIM + n0 + wc * 64 + nf * 16 + fr,
                    acc[mf][nf][j] * w);
      }
    }
}

extern "C" void kernel_launch(void* const* d_in, const int* in_sizes, int n_in,
                              void* d_out, int out_size, void* d_ws, size_t ws_size,
                              hipStream_t stream) {
  const float* x  = (const float*)d_in[0];
  const float* gw = (const float*)d_in[1];
  const float* wg = (const float*)d_in[2];
  const float* wu = (const float*)d_in[3];
  const float* wd = (const float*)d_in[4];
  float* out = (float*)d_out;

  char* ws = (char*)d_ws;
  unsigned short* xbf = (unsigned short*)ws;                       // 8,388,608 B
  unsigned short* h   = (unsigned short*)(ws + 8388608);           // 46,137,344 B
  int*   slots = (int*)(ws + 8388608 + 46137344);                  // 65,536 B
  float* wts   = (float*)(ws + 8388608 + 46137344 + 65536);        // 65,536 B
  int*   cnt   = (int*)(ws + 8388608 + 46137344 + 131072);         // 32 B

  hipMemsetAsync(cnt, 0, NEXP * sizeof(int), stream);
  hipMemsetAsync(d_out, 0, (size_t)TTOK * DDIM * sizeof(float), stream);

  router_kernel<<<TTOK / 4, 256, 0, stream>>>(x, gw, xbf, cnt, slots, wts);
  gateup_kernel<<<11264, 256, 0, stream>>>(xbf, wg, wu, cnt, slots, h);
  down_kernel<<<2048, 256, 0, stream>>>(h, wd, cnt, slots, wts, out);
}